// Round 7
// baseline (1031.068 us; speedup 1.0000x reference)
//
#include <hip/hip_runtime.h>
#include <hip/hip_bf16.h>

// Swin-style block for B=2, H=W=256, C=180, WS=8, SH=4, NH=6, HD=30.
// Pipeline: prep -> LN1(+roll+win) -> QKV (bnloop) -> zeropad -> attention ->
//           projN192 (+residual, full-row epilogue) -> LN2 -> 8 row-bands of
//           [FC1 bnloop+gelu(halo) -> dwconv+gelu -> FC2N192 K=768 full-row RMW].

using short8 = __attribute__((ext_vector_type(8))) short;
using f32x4  = __attribute__((ext_vector_type(4))) float;

constexpr int   ROWS   = 131072;               // B * H * W
constexpr float SCALE_ = 0.18257418583505536f; // 30^-0.5

// ---- workspace layout (bytes) ----
constexpr size_t OFF_WQ    = 0;                             // [576][192] bf16
constexpr size_t OFF_WP    = OFF_WQ   + 576*192*2;          // [192][192] bf16
constexpr size_t OFF_WF1   = OFF_WP   + 192*192*2;          // [768][192] bf16
constexpr size_t OFF_WF2T  = OFF_WF1  + 768*192*2;          // [192][768] bf16 (K-padded)
constexpr size_t OFF_BQ    = OFF_WF2T + 192*768*2;
constexpr size_t OFF_BP    = OFF_BQ   + 576*4;
constexpr size_t OFF_BF1   = OFF_BP   + 192*4;
constexpr size_t OFF_BF2   = OFF_BF1  + 768*4;
constexpr size_t OFF_BIASF = OFF_BF2  + 192*4;              // [6][64][64] f32
constexpr size_t OFF_WDWT  = OFF_BIASF + 6*4096*4;          // [9][768] f32
constexpr size_t OFF_BDW   = OFF_WDWT + 9*768*4;            // [768] f32
constexpr size_t OFF_R1    = 1048576;                       // 1 MiB aligned
constexpr size_t SZ_R      = (size_t)ROWS * 192 * 2;        // 50,331,648
constexpr size_t OFF_R2    = OFF_R1 + SZ_R;
constexpr size_t OFF_R3    = OFF_R2 + SZ_R;
constexpr size_t WS_NEEDED = OFF_R3 + SZ_R;                 // ~152 MB
static_assert(OFF_BDW + 768*4 <= OFF_R1, "weights overlap R1");
static_assert((size_t)66*256*768*2 <= SZ_R, "m1 band overflows R2");

__device__ __forceinline__ unsigned short f2bf(float f) {
    __hip_bfloat16 h = __float2bfloat16(f);
    return *reinterpret_cast<unsigned short*>(&h);
}
__device__ __forceinline__ float bf2f(unsigned short u) {
    union { unsigned int i; float f; } x; x.i = ((unsigned int)u) << 16; return x.f;
}
__device__ __forceinline__ float gelu_f(float x) {
    return 0.5f * x * (1.0f + erff(x * 0.70710678118654752f));
}

// ---------------- weight prep ----------------------------------------------
__global__ __launch_bounds__(256) void prep_kernel(
    const float* __restrict__ qkv_w, const float* __restrict__ qkv_b,
    const float* __restrict__ proj_w, const float* __restrict__ proj_b,
    const float* __restrict__ fc1_w, const float* __restrict__ fc1_b,
    const float* __restrict__ fc2_w, const float* __restrict__ fc2_b,
    const float* __restrict__ rpt,
    const float* __restrict__ dw_w, const float* __restrict__ dw_b,
    unsigned short* __restrict__ wq, unsigned short* __restrict__ wp,
    unsigned short* __restrict__ wf1, unsigned short* __restrict__ wf2t,
    float* __restrict__ bq, float* __restrict__ bp,
    float* __restrict__ bf1, float* __restrict__ bf2,
    float* __restrict__ biasf,
    float* __restrict__ wdwT, float* __restrict__ bdw)
{
    int idx = blockIdx.x * 256 + threadIdx.x;
    constexpr int E1 = 576*192;
    constexpr int E2 = E1 + 192*192;
    constexpr int E3 = E2 + 768*192;
    constexpr int E4 = E3 + 192*768;
    constexpr int E5 = E4 + 576;
    constexpr int E6 = E5 + 192;
    constexpr int E7 = E6 + 768;
    constexpr int E8 = E7 + 192;
    constexpr int E9 = E8 + 6*4096;
    constexpr int E10 = E9 + 9*768;
    constexpr int E11 = E10 + 768;
    if (idx < E1) {
        int n = idx / 192, kx = idx % 192;
        float v = 0.f;
        if (n < 540 && kx < 180) { v = qkv_w[kx*540 + n]; if (n < 180) v *= SCALE_; }
        wq[idx] = f2bf(v);
    } else if (idx < E2) {
        int j = idx - E1; int n = j / 192, kx = j % 192;
        wp[j] = f2bf((n < 180 && kx < 180) ? proj_w[kx*180 + n] : 0.f);
    } else if (idx < E3) {
        int j = idx - E2; int n = j / 192, kx = j % 192;
        wf1[j] = f2bf((n < 720 && kx < 180) ? fc1_w[kx*720 + n] : 0.f);
    } else if (idx < E4) {
        int j = idx - E3; int n = j / 768, kx = j % 768;
        wf2t[j] = f2bf((n < 180 && kx < 720) ? fc2_w[kx*180 + n] : 0.f);
    } else if (idx < E5) {
        int n = idx - E4;
        float v = (n < 540) ? qkv_b[n] : 0.f; if (n < 180) v *= SCALE_;
        bq[n] = v;
    } else if (idx < E6) {
        int n = idx - E5; bp[n] = (n < 180) ? proj_b[n] : 0.f;
    } else if (idx < E7) {
        int n = idx - E6; bf1[n] = (n < 720) ? fc1_b[n] : 0.f;
    } else if (idx < E8) {
        int n = idx - E7; bf2[n] = (n < 180) ? fc2_b[n] : 0.f;
    } else if (idx < E9) {
        int j = idx - E8;
        int hh = j / 4096, t = j & 4095;
        int n = t >> 6, m = t & 63;
        int rid = ((n>>3) - (m>>3) + 7)*15 + ((n&7) - (m&7) + 7);
        biasf[j] = rpt[rid*6 + hh];
    } else if (idx < E10) {
        int j = idx - E9;
        int tap = j / 768, c = j % 768;
        wdwT[j] = (c < 720) ? dw_w[c*9 + tap] : 0.f;
    } else if (idx < E11) {
        int c = idx - E10;
        bdw[c] = (c < 720) ? dw_b[c] : 0.f;
    }
}

// ---------------- LN (ROLL=1: fused cyclic-shift + window partition) -------
template<int ROLL>
__global__ __launch_bounds__(256) void ln_kernel(const float* __restrict__ x,
    const float* __restrict__ g, const float* __restrict__ bsh,
    unsigned short* __restrict__ out)
{
    int row  = blockIdx.x * 4 + (threadIdx.x >> 6);
    int lane = threadIdx.x & 63;
    size_t src;
    if (ROLL) {
        int b    = row >> 16;
        int widx = (row >> 6) & 1023;
        int n    = row & 63;
        int hr   = ((widx >> 5) << 3) + (n >> 3);
        int wr   = ((widx & 31) << 3) + (n & 7);
        int h2   = (hr + 4) & 255;
        int w2   = (wr + 4) & 255;
        src = ((size_t)b << 16) + (h2 << 8) + w2;
    } else {
        src = (size_t)row;
    }
    const float* xr = x + src * 180;
    float v1 = xr[lane];
    float v2 = xr[lane + 64];
    float v3 = (lane < 52) ? xr[lane + 128] : 0.0f;
    float s1 = v1 + v2 + v3;
    float s2 = v1*v1 + v2*v2 + v3*v3;
    #pragma unroll
    for (int o = 32; o > 0; o >>= 1) { s1 += __shfl_xor(s1, o); s2 += __shfl_xor(s2, o); }
    float mean = s1 * (1.0f/180.0f);
    float var  = s2 * (1.0f/180.0f) - mean*mean;
    float rstd = rsqrtf(var + 1e-5f);
    unsigned short* orow = out + (size_t)row * 192;
    orow[lane]      = f2bf((v1 - mean)*rstd*g[lane]      + bsh[lane]);
    orow[lane + 64] = f2bf((v2 - mean)*rstd*g[lane + 64] + bsh[lane + 64]);
    if (lane < 52) orow[lane + 128] = f2bf((v3 - mean)*rstd*g[lane + 128] + bsh[lane + 128]);
    else           orow[lane + 128] = 0;
}

// ---------------- zero the d=30,31 K-pads of q/k/vT ------------------------
__global__ __launch_bounds__(256) void zeropad_kernel(unsigned int* q, unsigned int* k, unsigned int* v)
{
    int idx = blockIdx.x * 256 + threadIdx.x;   // < 12288*192
    int wid = idx / 192, t = idx % 192;
    if (t < 64)       q[wid*1024 + t*16 + 15] = 0;
    else if (t < 128) k[wid*1024 + (t-64)*16 + 15] = 0;
    else              v[wid*1024 + 960 + (t-128)] = 0;
}

// ---------------- 64-row GEMM, A-panel resident in LDS, bn loop inside -----
// K fixed = 192 (6 steps of 32). A [M][192], Bt [NBN*64][192].
// MODE 0: QKV scatter (NBN=9); MODE 2: FC1 + gelu -> bf16 [.][768] (NBN=12).
template<int MODE, int NBN>
__global__ __launch_bounds__(256) void gemm_bnloop(
    const unsigned short* __restrict__ A, const unsigned short* __restrict__ Bt,
    const float* __restrict__ bias,
    unsigned short* __restrict__ oq, unsigned short* __restrict__ ok2,
    unsigned short* __restrict__ ov, unsigned short* __restrict__ obf)
{
    __shared__ __align__(16) unsigned short As[6*64*40];   // 30720 B
    __shared__ __align__(16) unsigned short Bs[6*64*40];   // 30720 B
    const int tid  = threadIdx.x;
    const int bm   = blockIdx.x;
    const int lane = tid & 63;
    const int wv   = tid >> 6;
    const int wr   = wv >> 1, wc = wv & 1;
    const int l15  = lane & 15, l4 = lane >> 4;
    const int r    = tid >> 2;             // 0..63
    const int kk   = (tid & 3) << 3;       // 0,8,16,24

    // stage A panel once (6 uint4 per thread)
    const size_t abase = (size_t)(bm*64 + r) * 192 + kk;
    #pragma unroll
    for (int kt = 0; kt < 6; kt++)
        *(uint4*)&As[kt*2560 + r*40 + kk] = *(const uint4*)&A[abase + kt*32];

    const size_t bstep = (size_t)r * 192 + kk;
    for (int bn = 0; bn < NBN; bn++) {
        #pragma unroll
        for (int kt = 0; kt < 6; kt++)
            *(uint4*)&Bs[kt*2560 + r*40 + kk] = *(const uint4*)&Bt[(size_t)bn*64*192 + bstep + kt*32];
        __syncthreads();   // first pass also covers A staging

        f32x4 acc[2][2];
        #pragma unroll
        for (int i = 0; i < 2; i++)
            #pragma unroll
            for (int j = 0; j < 2; j++) acc[i][j] = f32x4{0.f,0.f,0.f,0.f};
        #pragma unroll
        for (int kt = 0; kt < 6; kt++) {
            short8 af[2], bf[2];
            #pragma unroll
            for (int fm = 0; fm < 2; fm++) af[fm] = *(const short8*)&As[kt*2560 + (wr*32 + fm*16 + l15)*40 + l4*8];
            #pragma unroll
            for (int fn = 0; fn < 2; fn++) bf[fn] = *(const short8*)&Bs[kt*2560 + (wc*32 + fn*16 + l15)*40 + l4*8];
            #pragma unroll
            for (int fm = 0; fm < 2; fm++)
                #pragma unroll
                for (int fn = 0; fn < 2; fn++)
                    acc[fm][fn] = __builtin_amdgcn_mfma_f32_16x16x32_bf16(af[fm], bf[fn], acc[fm][fn], 0, 0, 0);
        }
        __syncthreads();   // Bs reads done before next-iteration staging

        #pragma unroll
        for (int fm = 0; fm < 2; fm++) {
          #pragma unroll
          for (int fn = 0; fn < 2; fn++) {
            #pragma unroll
            for (int rr = 0; rr < 4; rr++) {
                int grow = bm*64 + wr*32 + fm*16 + l4*4 + rr;
                int gcol = bn*64 + wc*32 + fn*16 + l15;
                float v = acc[fm][fn][rr] + bias[gcol];
                if (MODE == 0) {                   // QKV scatter (q has SCALE baked in)
                    if (gcol < 540) {
                        int which = (gcol >= 360) ? 2 : (gcol >= 180 ? 1 : 0);
                        int cc = gcol - which*180;
                        int hh = cc / 30;
                        int dd = cc - hh*30;
                        size_t wid = (size_t)(grow >> 6)*6 + hh;
                        if (which == 0)      oq [wid*2048 + (grow & 63)*32 + dd] = f2bf(v);
                        else if (which == 1) ok2[wid*2048 + (grow & 63)*32 + dd] = f2bf(v);
                        else                 ov [wid*2048 + dd*64 + (grow & 63)] = f2bf(v);
                    }
                } else {                           // FC1 + exact GELU -> bf16 [.][768]
                    obf[(size_t)grow*768 + gcol] = f2bf(gelu_f(v));
                }
            }
          }
        }
    }
}

// ---------------- full-width N=192 GEMM with f32 full-row epilogue ---------
// MODE 0 (proj): out[orow] = x[orow] + C + bias, orow = rolled window-reverse.
// MODE 1 (FC2):  out[row] += C + bias (out pre-offset to band start).
template<int M_BLK, int MODE>
__global__ __launch_bounds__(256) void gemmN192(
    const unsigned short* __restrict__ A, const unsigned short* __restrict__ Bt,
    const float* __restrict__ bias, int K, int lda, int ldb,
    const float* __restrict__ xres, float* __restrict__ out)
{
    constexpr int MB = M_BLK / 16;
    constexpr int LDS_STAGE = (M_BLK*40 + 192*40) * 2;
    constexpr int LDS_CST   = M_BLK * 180 * 4;
    constexpr int LDSZ = LDS_STAGE > LDS_CST ? LDS_STAGE : LDS_CST;
    __shared__ __align__(16) char lds[LDSZ];
    unsigned short* As = (unsigned short*)lds;
    unsigned short* Bs = As + M_BLK*40;
    float* Cst = (float*)lds;

    const int tid  = threadIdx.x;
    const int bm   = blockIdx.x;
    const int lane = tid & 63;
    const int wv   = tid >> 6;            // 0..3, owns cols [wv*48, wv*48+48)
    const int l15  = lane & 15, l4 = lane >> 4;
    const int r    = tid >> 2;            // 0..63
    const int kk   = (tid & 3) << 3;

    f32x4 acc[MB][3];
    #pragma unroll
    for (int m = 0; m < MB; m++)
        #pragma unroll
        for (int nb = 0; nb < 3; nb++) acc[m][nb] = f32x4{0.f,0.f,0.f,0.f};

    const size_t abase = (size_t)(bm*M_BLK + r) * (size_t)lda + kk;
    const size_t bbase = (size_t)r * (size_t)ldb + kk;

    for (int kt = 0; kt < K; kt += 32) {
        if (M_BLK == 64 || tid < M_BLK*4)
            *(uint4*)&As[r*40 + kk] = *(const uint4*)&A[abase + kt];
        #pragma unroll
        for (int jj = 0; jj < 3; jj++)
            *(uint4*)&Bs[(r + jj*64)*40 + kk] = *(const uint4*)&Bt[bbase + (size_t)jj*64*ldb + kt];
        __syncthreads();
        short8 af[MB], bf[3];
        #pragma unroll
        for (int m = 0; m < MB; m++) af[m] = *(const short8*)&As[(m*16 + l15)*40 + l4*8];
        #pragma unroll
        for (int nb = 0; nb < 3; nb++) bf[nb] = *(const short8*)&Bs[(wv*48 + nb*16 + l15)*40 + l4*8];
        #pragma unroll
        for (int m = 0; m < MB; m++)
            #pragma unroll
            for (int nb = 0; nb < 3; nb++)
                acc[m][nb] = __builtin_amdgcn_mfma_f32_16x16x32_bf16(af[m], bf[nb], acc[m][nb], 0, 0, 0);
        __syncthreads();
    }

    // stage C in LDS (f32), aliasing As/Bs (dead after last barrier)
    #pragma unroll
    for (int m = 0; m < MB; m++)
      #pragma unroll
      for (int nb = 0; nb < 3; nb++)
        #pragma unroll
        for (int rr = 0; rr < 4; rr++) {
            int tok = m*16 + l4*4 + rr;
            int col = wv*48 + nb*16 + l15;
            if (col < 180) Cst[tok*180 + col] = acc[m][nb][rr];
        }
    __syncthreads();

    // cooperative full-row epilogue: 4 threads per token, f32x4 ops
    for (int idx = tid; idx < M_BLK*4; idx += 256) {
        int tok = idx >> 2, j = idx & 3;
        int c0  = j * 48;
        int cnt = (j == 3) ? 36 : 48;
        size_t orow;
        if (MODE == 0) {
            int grow = bm*M_BLK + tok;
            int wig  = grow >> 6;
            int b_   = wig >> 10, wi = wig & 1023, ti = grow & 63;
            int h2   = (((wi >> 5) << 3) + (ti >> 3) + 4) & 255;
            int w2   = (((wi & 31) << 3) + (ti & 7) + 4) & 255;
            orow = ((size_t)b_ << 16) + (h2 << 8) + w2;
        } else {
            orow = (size_t)(bm*M_BLK + tok);
        }
        float*       op = out  + orow*180 + c0;
        const float* cp = &Cst[tok*180 + c0];
        const float* bb = bias + c0;
        if (MODE == 0) {
            const float* xp = xres + orow*180 + c0;
            for (int i = 0; i < cnt; i += 4) {
                f32x4 ov = *(const f32x4*)&xp[i] + *(const f32x4*)&cp[i] + *(const f32x4*)&bb[i];
                *(f32x4*)&op[i] = ov;
            }
        } else {
            for (int i = 0; i < cnt; i += 4) {
                f32x4 ov = *(const f32x4*)&op[i];
                ov += *(const f32x4*)&cp[i] + *(const f32x4*)&bb[i];
                *(f32x4*)&op[i] = ov;
            }
        }
    }
}

// ---------------- fused window attention: one wave per (window, head) ------
__global__ __launch_bounds__(64) void attn_kernel(
    const unsigned short* __restrict__ q, const unsigned short* __restrict__ k,
    const unsigned short* __restrict__ vt, const float* __restrict__ biasf,
    unsigned short* __restrict__ aout)
{
    __shared__ __align__(16) unsigned short P[64*72];
    const int wid  = blockIdx.x;          // b_*6 + head
    const int b_   = wid / 6, hh = wid % 6;
    const int lane = threadIdx.x;
    const int l15  = lane & 15, l4 = lane >> 4;

    const unsigned short* qb = q  + (size_t)wid*2048;
    const unsigned short* kb = k  + (size_t)wid*2048;
    const unsigned short* vb = vt + (size_t)wid*2048;

    short8 qf[4], kf[4];
    #pragma unroll
    for (int t = 0; t < 4; t++) {
        qf[t] = *(const short8*)&qb[(t*16 + l15)*32 + l4*8];
        kf[t] = *(const short8*)&kb[(t*16 + l15)*32 + l4*8];
    }
    f32x4 s[4][4];
    #pragma unroll
    for (int m = 0; m < 4; m++)
        #pragma unroll
        for (int n = 0; n < 4; n++)
            s[m][n] = __builtin_amdgcn_mfma_f32_16x16x32_bf16(qf[m], kf[n], f32x4{0.f,0.f,0.f,0.f}, 0, 0, 0);

    const int wi = b_ & 1023;
    const int wh = wi >> 5, ww = wi & 31;
    const bool edge = (wh == 31) || (ww == 31);
    const float* bh = biasf + hh*4096;
    #pragma unroll
    for (int m = 0; m < 4; m++) {
      #pragma unroll
      for (int rr = 0; rr < 4; rr++) {
        int ni = m*16 + l4*4 + rr;
        int ln_n = 0;
        if (edge) {
            int rh = (wh < 31) ? 0 : (((ni >> 3) < 4) ? 1 : 2);
            int rw = (ww < 31) ? 0 : (((ni & 7) < 4) ? 1 : 2);
            ln_n = rh*3 + rw;
        }
        #pragma unroll
        for (int n = 0; n < 4; n++) {
            int mj = n*16 + l15;
            float add = bh[ni*64 + mj];
            if (edge) {
                int rh = (wh < 31) ? 0 : (((mj >> 3) < 4) ? 1 : 2);
                int rw = (ww < 31) ? 0 : (((mj & 7) < 4) ? 1 : 2);
                if (rh*3 + rw != ln_n) add -= 100.0f;
            }
            s[m][n][rr] += add;
        }
      }
    }
    #pragma unroll
    for (int m = 0; m < 4; m++) {
      #pragma unroll
      for (int rr = 0; rr < 4; rr++) {
        float mx = fmaxf(fmaxf(s[m][0][rr], s[m][1][rr]), fmaxf(s[m][2][rr], s[m][3][rr]));
        #pragma unroll
        for (int o = 8; o > 0; o >>= 1) mx = fmaxf(mx, __shfl_xor(mx, o));
        float sum = 0.f;
        #pragma unroll
        for (int n = 0; n < 4; n++) { float e = __expf(s[m][n][rr] - mx); s[m][n][rr] = e; sum += e; }
        #pragma unroll
        for (int o = 8; o > 0; o >>= 1) sum += __shfl_xor(sum, o);
        float inv = 1.0f / sum;
        int ni = m*16 + l4*4 + rr;
        #pragma unroll
        for (int n = 0; n < 4; n++) P[ni*72 + n*16 + l15] = f2bf(s[m][n][rr] * inv);
      }
    }
    __syncthreads();
    f32x4 po[4][2];
    #pragma unroll
    for (int m = 0; m < 4; m++)
        #pragma unroll
        for (int n = 0; n < 2; n++) po[m][n] = f32x4{0.f,0.f,0.f,0.f};
    #pragma unroll
    for (int ks = 0; ks < 2; ks++) {
        short8 pf[4], vf[2];
        #pragma unroll
        for (int m = 0; m < 4; m++) pf[m] = *(const short8*)&P[(m*16 + l15)*72 + ks*32 + l4*8];
        #pragma unroll
        for (int n = 0; n < 2; n++) vf[n] = *(const short8*)&vb[(n*16 + l15)*64 + ks*32 + l4*8];
        #pragma unroll
        for (int m = 0; m < 4; m++)
            #pragma unroll
            for (int n = 0; n < 2; n++)
                po[m][n] = __builtin_amdgcn_mfma_f32_16x16x32_bf16(pf[m], vf[n], po[m][n], 0, 0, 0);
    }
    #pragma unroll
    for (int m = 0; m < 4; m++)
      #pragma unroll
      for (int n = 0; n < 2; n++)
        #pragma unroll
        for (int rr = 0; rr < 4; rr++) {
            int ni = m*16 + l4*4 + rr;
            int dd = n*16 + l15;
            if (dd < 30)
                aout[((size_t)b_*64 + ni)*192 + hh*30 + dd] = f2bf(po[m][n][rr]);
        }
}

// ---------------- depthwise 3x3 conv + bias + exact GELU (64-row band) -----
__global__ __launch_bounds__(256) void dwconv_band(
    const unsigned short* __restrict__ m1, const float* __restrict__ wT,
    const float* __restrict__ bias, int h0, unsigned short* __restrict__ m2)
{
    const int hl  = blockIdx.x;            // 0..63 (band-local row)
    const int t   = threadIdx.x;
    const int cg  = t & 31;
    const int pl  = t >> 5;                // 0..7
    const int w0  = blockIdx.y * 64 + pl * 8;
    const int c   = blockIdx.z * 256 + cg * 8;   // 0..760

    float acc[8][8];
    float bv[8];
    *(f32x4*)&bv[0] = *(const f32x4*)&bias[c];
    *(f32x4*)&bv[4] = *(const f32x4*)&bias[c + 4];
    #pragma unroll
    for (int p = 0; p < 8; p++)
        #pragma unroll
        for (int i = 0; i < 8; i++) acc[p][i] = bv[i];

    const short8 zv = {0,0,0,0,0,0,0,0};
    #pragma unroll
    for (int dh = -1; dh <= 1; dh++) {
        int hg = h0 + hl + dh;
        if (hg < 0 || hg > 255) continue;
        const unsigned short* rb = m1 + (size_t)(hl + 1 + dh) * 256 * 768 + c;
        float f[10][8];
        #pragma unroll
        for (int j = 0; j < 10; j++) {
            int w2 = w0 - 1 + j;
            short8 v = (w2 < 0 || w2 > 255) ? zv : *(const short8*)&rb[(size_t)w2*768];
            #pragma unroll
            for (int i = 0; i < 8; i++) f[j][i] = bf2f((unsigned short)v[i]);
        }
        #pragma unroll
        for (int dw2 = 0; dw2 < 3; dw2++) {
            const float* wrow = wT + ((dh+1)*3 + dw2)*768 + c;
            float wt[8];
            *(f32x4*)&wt[0] = *(const f32x4*)&wrow[0];
            *(f32x4*)&wt[4] = *(const f32x4*)&wrow[4];
            #pragma unroll
            for (int p = 0; p < 8; p++)
                #pragma unroll
                for (int i = 0; i < 8; i++)
                    acc[p][i] += f[p + dw2][i] * wt[i];
        }
    }
    unsigned short* ob = m2 + ((size_t)hl*256 + w0)*768 + c;
    #pragma unroll
    for (int p = 0; p < 8; p++) {
        short8 o;
        #pragma unroll
        for (int i = 0; i < 8; i++) o[i] = (short)f2bf(gelu_f(acc[p][i]));
        *(short8*)&ob[(size_t)p*768] = o;
    }
}

extern "C" void kernel_launch(void* const* d_in, const int* in_sizes, int n_in,
                              void* d_out, int out_size, void* d_ws, size_t ws_size,
                              hipStream_t stream) {
    (void)in_sizes; (void)n_in; (void)out_size;
    if (ws_size < WS_NEEDED) return;
    const float* x      = (const float*)d_in[0];
    const float* n1g    = (const float*)d_in[1];
    const float* n1b    = (const float*)d_in[2];
    const float* qkv_w  = (const float*)d_in[3];
    const float* qkv_b  = (const float*)d_in[4];
    const float* rpt    = (const float*)d_in[5];
    const float* proj_w = (const float*)d_in[6];
    const float* proj_b = (const float*)d_in[7];
    const float* n2g    = (const float*)d_in[8];
    const float* n2b    = (const float*)d_in[9];
    const float* fc1_w  = (const float*)d_in[10];
    const float* fc1_b  = (const float*)d_in[11];
    const float* dw_w   = (const float*)d_in[12];
    const float* dw_b   = (const float*)d_in[13];
    const float* fc2_w  = (const float*)d_in[14];
    const float* fc2_b  = (const float*)d_in[15];
    float* out = (float*)d_out;
    char*  ws  = (char*)d_ws;

    unsigned short* wq   = (unsigned short*)(ws + OFF_WQ);
    unsigned short* wp   = (unsigned short*)(ws + OFF_WP);
    unsigned short* wf1  = (unsigned short*)(ws + OFF_WF1);
    unsigned short* wf2t = (unsigned short*)(ws + OFF_WF2T);
    float* bq    = (float*)(ws + OFF_BQ);
    float* bp    = (float*)(ws + OFF_BP);
    float* bf1   = (float*)(ws + OFF_BF1);
    float* bf2   = (float*)(ws + OFF_BF2);
    float* biasf = (float*)(ws + OFF_BIASF);
    float* wdwT  = (float*)(ws + OFF_WDWT);
    float* bdw   = (float*)(ws + OFF_BDW);
    unsigned short* R1 = (unsigned short*)(ws + OFF_R1);  // xw / attn_out / xn2
    unsigned short* R2 = (unsigned short*)(ws + OFF_R2);  // k / m1 band
    unsigned short* R3 = (unsigned short*)(ws + OFF_R3);  // vT / m2 band
    unsigned short* qp = (unsigned short*)d_out;          // padded Q (scratch)

    prep_kernel<<<1861, 256, 0, stream>>>(qkv_w, qkv_b, proj_w, proj_b, fc1_w, fc1_b,
                                          fc2_w, fc2_b, rpt, dw_w, dw_b,
                                          wq, wp, wf1, wf2t,
                                          bq, bp, bf1, bf2, biasf, wdwT, bdw);
    // LN1 + shift + window partition -> xw (R1, [131072][192] bf16, pads zeroed)
    ln_kernel<1><<<32768, 256, 0, stream>>>(x, n1g, n1b, R1);
    // QKV gemm (A-resident bn loop) -> q (d_out scratch) / k (R2) / vT (R3)
    gemm_bnloop<0, 9><<<2048, 256, 0, stream>>>(R1, wq, bq, qp, R2, R3, nullptr);
    zeropad_kernel<<<9216, 256, 0, stream>>>((unsigned int*)qp, (unsigned int*)R2, (unsigned int*)R3);
    // fused attention -> attn_out (R1; pad cols still zero from LN1)
    attn_kernel<<<12288, 64, 0, stream>>>(qp, R2, R3, biasf, R1);
    // proj + window-reverse + residual -> d_out (x1), full-row epilogue
    gemmN192<64, 0><<<2048, 256, 0, stream>>>(R1, wp, bp, 192, 192, 192, x, out);
    // LN2 -> xn2 (R1)
    ln_kernel<0><<<32768, 256, 0, stream>>>(out, n2g, n2b, R1);
    // MLP in 8 row-bands of 64 (halo'd FC1; single-pass K=768 FC2)
    for (int band = 0; band < 8; ++band) {
        const int b_img   = band >> 2;
        const int h0      = (band & 3) * 64;
        const int h_start = (h0 == 0) ? 0 : h0 - 1;
        const int h_end   = (h0 + 64 < 256) ? (h0 + 65) : 256;
        const int n_rows  = h_end - h_start;
        const int moff    = (h0 == 0) ? 1 : 0;
        const size_t arow0 = ((size_t)b_img*256 + h_start) * 256;
        const size_t pix0  = ((size_t)b_img*256 + h0) * 256;
        gemm_bnloop<2, 12><<<n_rows*4, 256, 0, stream>>>(
            R1 + arow0*192, wf1, bf1,
            nullptr, nullptr, nullptr, R2 + (size_t)moff*256*768);
        dwconv_band<<<dim3(64, 4, 3), 256, 0, stream>>>(R2, wdwT, bdw, h0, R3);
        gemmN192<32, 1><<<512, 256, 0, stream>>>(
            R3, wf2t, bf2, 768, 768, 768, nullptr, out + pix0*180);
    }
}

// Round 8
// 814.287 us; speedup vs baseline: 1.2662x; 1.2662x over previous
//
#include <hip/hip_runtime.h>
#include <hip/hip_bf16.h>

// Swin-style block for B=2, H=W=256, C=180, WS=8, SH=4, NH=6, HD=30.
// Pipeline: prep -> LN1(+roll+win) -> fused QKV+attention (one WG per window,
//           in-place on R1) -> projN192 (+residual) -> LN2 -> 8 row-bands of
//           [FC1+gelu(halo) -> dwconv+gelu -> FC2N192 K=768 full-row RMW].

using short8 = __attribute__((ext_vector_type(8))) short;
using f32x4  = __attribute__((ext_vector_type(4))) float;

constexpr int   ROWS   = 131072;               // B * H * W
constexpr float SCALE_ = 0.18257418583505536f; // 30^-0.5

// ---- workspace layout (bytes) ----
constexpr size_t OFF_WQ    = 0;                             // [6][3][32][192] bf16
constexpr size_t OFF_WP    = OFF_WQ   + 576*192*2;          // [192][192] bf16
constexpr size_t OFF_WF1   = OFF_WP   + 192*192*2;          // [768][192] bf16
constexpr size_t OFF_WF2T  = OFF_WF1  + 768*192*2;          // [192][768] bf16 (K-padded)
constexpr size_t OFF_BQ    = OFF_WF2T + 192*768*2;          // [6][3][32] f32
constexpr size_t OFF_BP    = OFF_BQ   + 576*4;
constexpr size_t OFF_BF1   = OFF_BP   + 192*4;
constexpr size_t OFF_BF2   = OFF_BF1  + 768*4;
constexpr size_t OFF_BIASF = OFF_BF2  + 192*4;              // [6][64][64] f32
constexpr size_t OFF_WDWT  = OFF_BIASF + 6*4096*4;          // [9][768] f32
constexpr size_t OFF_BDW   = OFF_WDWT + 9*768*4;            // [768] f32
constexpr size_t OFF_R1    = 1048576;                       // 1 MiB aligned
constexpr size_t SZ_R      = (size_t)ROWS * 192 * 2;        // 50,331,648
constexpr size_t OFF_R2    = OFF_R1 + SZ_R;
constexpr size_t OFF_R3    = OFF_R2 + SZ_R;
constexpr size_t WS_NEEDED = OFF_R3 + SZ_R;                 // ~152 MB
static_assert(OFF_BDW + 768*4 <= OFF_R1, "weights overlap R1");
static_assert((size_t)66*256*768*2 <= SZ_R, "m1 band overflows R2");

__device__ __forceinline__ unsigned short f2bf(float f) {
    __hip_bfloat16 h = __float2bfloat16(f);
    return *reinterpret_cast<unsigned short*>(&h);
}
__device__ __forceinline__ float bf2f(unsigned short u) {
    union { unsigned int i; float f; } x; x.i = ((unsigned int)u) << 16; return x.f;
}
__device__ __forceinline__ float gelu_f(float x) {
    return 0.5f * x * (1.0f + erff(x * 0.70710678118654752f));
}

// ---------------- weight prep ----------------------------------------------
// wq2 layout [head][which(q,k,v)][32 cols (30 real + 2 zero)][192 k] bf16,
// q slice has SCALE baked in; bq2 [head][which][32] f32 matching.
__global__ __launch_bounds__(256) void prep_kernel(
    const float* __restrict__ qkv_w, const float* __restrict__ qkv_b,
    const float* __restrict__ proj_w, const float* __restrict__ proj_b,
    const float* __restrict__ fc1_w, const float* __restrict__ fc1_b,
    const float* __restrict__ fc2_w, const float* __restrict__ fc2_b,
    const float* __restrict__ rpt,
    const float* __restrict__ dw_w, const float* __restrict__ dw_b,
    unsigned short* __restrict__ wq2, unsigned short* __restrict__ wp,
    unsigned short* __restrict__ wf1, unsigned short* __restrict__ wf2t,
    float* __restrict__ bq2, float* __restrict__ bp,
    float* __restrict__ bf1, float* __restrict__ bf2,
    float* __restrict__ biasf,
    float* __restrict__ wdwT, float* __restrict__ bdw)
{
    int idx = blockIdx.x * 256 + threadIdx.x;
    constexpr int E1 = 576*192;
    constexpr int E2 = E1 + 192*192;
    constexpr int E3 = E2 + 768*192;
    constexpr int E4 = E3 + 192*768;
    constexpr int E5 = E4 + 576;
    constexpr int E6 = E5 + 192;
    constexpr int E7 = E6 + 768;
    constexpr int E8 = E7 + 192;
    constexpr int E9 = E8 + 6*4096;
    constexpr int E10 = E9 + 9*768;
    constexpr int E11 = E10 + 768;
    if (idx < E1) {
        int n = idx / 192, kx = idx % 192;
        int hh = n / 96, rem = n % 96;
        int w  = rem / 32, c = rem % 32;
        float v = 0.f;
        if (c < 30 && kx < 180) {
            v = qkv_w[kx*540 + w*180 + hh*30 + c];
            if (w == 0) v *= SCALE_;
        }
        wq2[idx] = f2bf(v);
    } else if (idx < E2) {
        int j = idx - E1; int n = j / 192, kx = j % 192;
        wp[j] = f2bf((n < 180 && kx < 180) ? proj_w[kx*180 + n] : 0.f);
    } else if (idx < E3) {
        int j = idx - E2; int n = j / 192, kx = j % 192;
        wf1[j] = f2bf((n < 720 && kx < 180) ? fc1_w[kx*720 + n] : 0.f);
    } else if (idx < E4) {
        int j = idx - E3; int n = j / 768, kx = j % 768;
        wf2t[j] = f2bf((n < 180 && kx < 720) ? fc2_w[kx*180 + n] : 0.f);
    } else if (idx < E5) {
        int n = idx - E4;
        int hh = n / 96, rem = n % 96;
        int w  = rem / 32, c = rem % 32;
        float v = 0.f;
        if (c < 30) { v = qkv_b[w*180 + hh*30 + c]; if (w == 0) v *= SCALE_; }
        bq2[n] = v;
    } else if (idx < E6) {
        int n = idx - E5; bp[n] = (n < 180) ? proj_b[n] : 0.f;
    } else if (idx < E7) {
        int n = idx - E6; bf1[n] = (n < 720) ? fc1_b[n] : 0.f;
    } else if (idx < E8) {
        int n = idx - E7; bf2[n] = (n < 180) ? fc2_b[n] : 0.f;
    } else if (idx < E9) {
        int j = idx - E8;
        int hh = j / 4096, t = j & 4095;
        int n = t >> 6, m = t & 63;
        int rid = ((n>>3) - (m>>3) + 7)*15 + ((n&7) - (m&7) + 7);
        biasf[j] = rpt[rid*6 + hh];
    } else if (idx < E10) {
        int j = idx - E9;
        int tap = j / 768, c = j % 768;
        wdwT[j] = (c < 720) ? dw_w[c*9 + tap] : 0.f;
    } else if (idx < E11) {
        int c = idx - E10;
        bdw[c] = (c < 720) ? dw_b[c] : 0.f;
    }
}

// ---------------- LN (ROLL=1: fused cyclic-shift + window partition) -------
template<int ROLL>
__global__ __launch_bounds__(256) void ln_kernel(const float* __restrict__ x,
    const float* __restrict__ g, const float* __restrict__ bsh,
    unsigned short* __restrict__ out)
{
    int row  = blockIdx.x * 4 + (threadIdx.x >> 6);
    int lane = threadIdx.x & 63;
    size_t src;
    if (ROLL) {
        int b    = row >> 16;
        int widx = (row >> 6) & 1023;
        int n    = row & 63;
        int hr   = ((widx >> 5) << 3) + (n >> 3);
        int wr   = ((widx & 31) << 3) + (n & 7);
        int h2   = (hr + 4) & 255;
        int w2   = (wr + 4) & 255;
        src = ((size_t)b << 16) + (h2 << 8) + w2;
    } else {
        src = (size_t)row;
    }
    const float* xr = x + src * 180;
    float v1 = xr[lane];
    float v2 = xr[lane + 64];
    float v3 = (lane < 52) ? xr[lane + 128] : 0.0f;
    float s1 = v1 + v2 + v3;
    float s2 = v1*v1 + v2*v2 + v3*v3;
    #pragma unroll
    for (int o = 32; o > 0; o >>= 1) { s1 += __shfl_xor(s1, o); s2 += __shfl_xor(s2, o); }
    float mean = s1 * (1.0f/180.0f);
    float var  = s2 * (1.0f/180.0f) - mean*mean;
    float rstd = rsqrtf(var + 1e-5f);
    unsigned short* orow = out + (size_t)row * 192;
    orow[lane]      = f2bf((v1 - mean)*rstd*g[lane]      + bsh[lane]);
    orow[lane + 64] = f2bf((v2 - mean)*rstd*g[lane + 64] + bsh[lane + 64]);
    if (lane < 52) orow[lane + 128] = f2bf((v3 - mean)*rstd*g[lane + 128] + bsh[lane + 128]);
    else           orow[lane + 128] = 0;
}

// ---------------- fused QKV + attention: one WG (6 waves = 6 heads)/window -
// In-place: reads xw rows [bm*64,+64), writes attn_out to the same rows.
// LDS (shorts): AsQ [0,15360)  As=[6kt][64][40] -> later QS=[6][64][32]
//               KS  [15360,27648) = [6][64][32]
//               VT  [27648,39936) = [6][32][64]  (tok-XOR swizzled)
//               P   aliases AsQ+KS = [6][64][72] (after barrier 3)
__global__ __launch_bounds__(384, 3) void fused_qkv_attn(
    unsigned short* __restrict__ xw,         // R1, in-place
    const unsigned short* __restrict__ wq2, const float* __restrict__ bq2,
    const float* __restrict__ biasf)
{
    __shared__ __align__(16) unsigned short lds[39936];   // 79,872 B
    unsigned short* AsQ = lds;
    unsigned short* KS  = lds + 15360;
    unsigned short* VT  = lds + 27648;
    unsigned short* P   = lds;

    const int bm   = blockIdx.x;             // window id = b*1024 + wi
    const int tid  = threadIdx.x;
    const int hh   = tid >> 6;               // wave = head
    const int lane = tid & 63;
    const int l15  = lane & 15, l4 = lane >> 4;

    // ---- phase 0: stage A panel [64][192] -> As [6kt][64][40]
    {
        const unsigned short* Arow = xw + (size_t)bm * 12288;
        #pragma unroll
        for (int j = 0; j < 4; j++) {
            int c   = tid + j*384;
            int row = c / 24;
            int s   = (c % 24) * 8;
            int kt  = s >> 5, kk = s & 31;
            *(uint4*)&AsQ[kt*2560 + row*40 + kk] = *(const uint4*)&Arow[row*192 + s];
        }
    }
    __syncthreads();

    // ---- phase 1: q gemm (hold accs), k gemm -> KS, v gemm -> VT
    f32x4 qa[2][4];
    #pragma unroll
    for (int ct = 0; ct < 2; ct++)
        #pragma unroll
        for (int m = 0; m < 4; m++) qa[ct][m] = f32x4{0.f,0.f,0.f,0.f};
    {   // q (w=0)
        #pragma unroll
        for (int kt = 0; kt < 6; kt++) {
            short8 af[4];
            #pragma unroll
            for (int m = 0; m < 4; m++) af[m] = *(const short8*)&AsQ[kt*2560 + (m*16 + l15)*40 + l4*8];
            #pragma unroll
            for (int ct = 0; ct < 2; ct++) {
                short8 bf = *(const short8*)&wq2[(size_t)(hh*96 + ct*16 + l15)*192 + kt*32 + l4*8];
                #pragma unroll
                for (int m = 0; m < 4; m++)
                    qa[ct][m] = __builtin_amdgcn_mfma_f32_16x16x32_bf16(af[m], bf, qa[ct][m], 0, 0, 0);
            }
        }
    }
    {   // k (w=1) -> KS
        f32x4 ka[2][4];
        #pragma unroll
        for (int ct = 0; ct < 2; ct++)
            #pragma unroll
            for (int m = 0; m < 4; m++) ka[ct][m] = f32x4{0.f,0.f,0.f,0.f};
        #pragma unroll
        for (int kt = 0; kt < 6; kt++) {
            short8 af[4];
            #pragma unroll
            for (int m = 0; m < 4; m++) af[m] = *(const short8*)&AsQ[kt*2560 + (m*16 + l15)*40 + l4*8];
            #pragma unroll
            for (int ct = 0; ct < 2; ct++) {
                short8 bf = *(const short8*)&wq2[(size_t)(hh*96 + 32 + ct*16 + l15)*192 + kt*32 + l4*8];
                #pragma unroll
                for (int m = 0; m < 4; m++)
                    ka[ct][m] = __builtin_amdgcn_mfma_f32_16x16x32_bf16(af[m], bf, ka[ct][m], 0, 0, 0);
            }
        }
        #pragma unroll
        for (int ct = 0; ct < 2; ct++)
          #pragma unroll
          for (int m = 0; m < 4; m++)
            #pragma unroll
            for (int rr = 0; rr < 4; rr++) {
                int tok = m*16 + l4*4 + rr;
                int dd  = ct*16 + l15;
                KS[hh*2048 + tok*32 + dd] = f2bf(ka[ct][m][rr] + bq2[hh*96 + 32 + dd]);
            }
    }
    {   // v (w=2) -> VT (swizzled)
        f32x4 va[2][4];
        #pragma unroll
        for (int ct = 0; ct < 2; ct++)
            #pragma unroll
            for (int m = 0; m < 4; m++) va[ct][m] = f32x4{0.f,0.f,0.f,0.f};
        #pragma unroll
        for (int kt = 0; kt < 6; kt++) {
            short8 af[4];
            #pragma unroll
            for (int m = 0; m < 4; m++) af[m] = *(const short8*)&AsQ[kt*2560 + (m*16 + l15)*40 + l4*8];
            #pragma unroll
            for (int ct = 0; ct < 2; ct++) {
                short8 bf = *(const short8*)&wq2[(size_t)(hh*96 + 64 + ct*16 + l15)*192 + kt*32 + l4*8];
                #pragma unroll
                for (int m = 0; m < 4; m++)
                    va[ct][m] = __builtin_amdgcn_mfma_f32_16x16x32_bf16(af[m], bf, va[ct][m], 0, 0, 0);
            }
        }
        #pragma unroll
        for (int ct = 0; ct < 2; ct++)
          #pragma unroll
          for (int m = 0; m < 4; m++)
            #pragma unroll
            for (int rr = 0; rr < 4; rr++) {
                int tok = m*16 + l4*4 + rr;
                int dd  = ct*16 + l15;
                int tsw = tok ^ ((dd & 7) << 3);
                VT[hh*2048 + dd*64 + tsw] = f2bf(va[ct][m][rr] + bq2[hh*96 + 64 + dd]);
            }
    }
    __syncthreads();   // As dead everywhere -> QS may overwrite

    // ---- phase 2: q accs -> QS (transpose bounce through dead As region)
    #pragma unroll
    for (int ct = 0; ct < 2; ct++)
      #pragma unroll
      for (int m = 0; m < 4; m++)
        #pragma unroll
        for (int rr = 0; rr < 4; rr++) {
            int tok = m*16 + l4*4 + rr;
            int dd  = ct*16 + l15;
            AsQ[hh*2048 + tok*32 + dd] = f2bf(qa[ct][m][rr] + bq2[hh*96 + dd]);
        }

    // ---- phase 3: load q/k frags (own head), then free QS/KS for P
    short8 qf[4], kf[4];
    #pragma unroll
    for (int t = 0; t < 4; t++) {
        qf[t] = *(const short8*)&AsQ[hh*2048 + (t*16 + l15)*32 + l4*8];
        kf[t] = *(const short8*)&KS [hh*2048 + (t*16 + l15)*32 + l4*8];
    }
    __syncthreads();   // all frags loaded -> P may overwrite QS/KS

    // ---- phase 4: QK^T + bias/mask + softmax + PV (verified attn code)
    f32x4 s[4][4];
    #pragma unroll
    for (int m = 0; m < 4; m++)
        #pragma unroll
        for (int n = 0; n < 4; n++)
            s[m][n] = __builtin_amdgcn_mfma_f32_16x16x32_bf16(qf[m], kf[n], f32x4{0.f,0.f,0.f,0.f}, 0, 0, 0);

    const int wi = bm & 1023;
    const int wh = wi >> 5, ww = wi & 31;
    const bool edge = (wh == 31) || (ww == 31);
    const float* bh = biasf + hh*4096;
    #pragma unroll
    for (int m = 0; m < 4; m++) {
      #pragma unroll
      for (int rr = 0; rr < 4; rr++) {
        int ni = m*16 + l4*4 + rr;
        int ln_n = 0;
        if (edge) {
            int rh = (wh < 31) ? 0 : (((ni >> 3) < 4) ? 1 : 2);
            int rw = (ww < 31) ? 0 : (((ni & 7) < 4) ? 1 : 2);
            ln_n = rh*3 + rw;
        }
        #pragma unroll
        for (int n = 0; n < 4; n++) {
            int mj = n*16 + l15;
            float add = bh[ni*64 + mj];
            if (edge) {
                int rh = (wh < 31) ? 0 : (((mj >> 3) < 4) ? 1 : 2);
                int rw = (ww < 31) ? 0 : (((mj & 7) < 4) ? 1 : 2);
                if (rh*3 + rw != ln_n) add -= 100.0f;
            }
            s[m][n][rr] += add;
        }
      }
    }
    #pragma unroll
    for (int m = 0; m < 4; m++) {
      #pragma unroll
      for (int rr = 0; rr < 4; rr++) {
        float mx = fmaxf(fmaxf(s[m][0][rr], s[m][1][rr]), fmaxf(s[m][2][rr], s[m][3][rr]));
        #pragma unroll
        for (int o = 8; o > 0; o >>= 1) mx = fmaxf(mx, __shfl_xor(mx, o));
        float sum = 0.f;
        #pragma unroll
        for (int n = 0; n < 4; n++) { float e = __expf(s[m][n][rr] - mx); s[m][n][rr] = e; sum += e; }
        #pragma unroll
        for (int o = 8; o > 0; o >>= 1) sum += __shfl_xor(sum, o);
        float inv = 1.0f / sum;
        int ni = m*16 + l4*4 + rr;
        #pragma unroll
        for (int n = 0; n < 4; n++) P[hh*4608 + ni*72 + n*16 + l15] = f2bf(s[m][n][rr] * inv);
      }
    }
    // PV
    f32x4 po[4][2];
    #pragma unroll
    for (int m = 0; m < 4; m++)
        #pragma unroll
        for (int n = 0; n < 2; n++) po[m][n] = f32x4{0.f,0.f,0.f,0.f};
    #pragma unroll
    for (int ksx = 0; ksx < 2; ksx++) {
        short8 pf[4], vf[2];
        #pragma unroll
        for (int m = 0; m < 4; m++) pf[m] = *(const short8*)&P[hh*4608 + (m*16 + l15)*72 + ksx*32 + l4*8];
        #pragma unroll
        for (int n = 0; n < 2; n++) {
            int dd  = n*16 + l15;
            int g   = (ksx*4 + l4) ^ (dd & 7);       // swizzled 8-tok group
            vf[n] = *(const short8*)&VT[hh*2048 + dd*64 + g*8];
        }
        #pragma unroll
        for (int m = 0; m < 4; m++)
            #pragma unroll
            for (int n = 0; n < 2; n++)
                po[m][n] = __builtin_amdgcn_mfma_f32_16x16x32_bf16(pf[m], vf[n], po[m][n], 0, 0, 0);
    }
    // write attn_out in-place (cols <180; pads stay zero from LN1)
    unsigned short* ob = xw + (size_t)bm * 12288;
    #pragma unroll
    for (int m = 0; m < 4; m++)
      #pragma unroll
      for (int n = 0; n < 2; n++)
        #pragma unroll
        for (int rr = 0; rr < 4; rr++) {
            int ni = m*16 + l4*4 + rr;
            int dd = n*16 + l15;
            if (dd < 30) ob[ni*192 + hh*30 + dd] = f2bf(po[m][n][rr]);
        }
}

// ---------------- FC1: 64x64-tile GEMM (bm on x, bn on y) + gelu -----------
__global__ __launch_bounds__(256) void fc1_gemm64(
    const unsigned short* __restrict__ A, const unsigned short* __restrict__ Bt,
    const float* __restrict__ bias, unsigned short* __restrict__ obf)
{
    __shared__ __align__(16) unsigned short As[64*40];
    __shared__ __align__(16) unsigned short Bs[64*40];
    const int tid  = threadIdx.x;
    const int bm   = blockIdx.x, bn = blockIdx.y;
    const int lane = tid & 63;
    const int wv   = tid >> 6;
    const int wr   = wv >> 1, wc = wv & 1;
    const int l15  = lane & 15, l4 = lane >> 4;
    const int r    = tid >> 2;
    const int kk   = (tid & 3) << 3;

    f32x4 acc[2][2];
    #pragma unroll
    for (int i = 0; i < 2; i++)
        #pragma unroll
        for (int j = 0; j < 2; j++) acc[i][j] = f32x4{0.f, 0.f, 0.f, 0.f};

    const size_t abase = (size_t)(bm*64 + r) * 192 + kk;
    const size_t bbase = (size_t)(bn*64 + r) * 192 + kk;
    const int lds_wi = r*40 + kk;

    for (int kt = 0; kt < 192; kt += 32) {
        *(uint4*)&As[lds_wi] = *(const uint4*)&A[abase + kt];
        *(uint4*)&Bs[lds_wi] = *(const uint4*)&Bt[bbase + kt];
        __syncthreads();
        short8 af[2], bf[2];
        #pragma unroll
        for (int fm = 0; fm < 2; fm++) af[fm] = *(const short8*)&As[(wr*32 + fm*16 + l15)*40 + l4*8];
        #pragma unroll
        for (int fn = 0; fn < 2; fn++) bf[fn] = *(const short8*)&Bs[(wc*32 + fn*16 + l15)*40 + l4*8];
        #pragma unroll
        for (int fm = 0; fm < 2; fm++)
            #pragma unroll
            for (int fn = 0; fn < 2; fn++)
                acc[fm][fn] = __builtin_amdgcn_mfma_f32_16x16x32_bf16(af[fm], bf[fn], acc[fm][fn], 0, 0, 0);
        __syncthreads();
    }
    #pragma unroll
    for (int fm = 0; fm < 2; fm++)
      #pragma unroll
      for (int fn = 0; fn < 2; fn++)
        #pragma unroll
        for (int rr = 0; rr < 4; rr++) {
            int grow = bm*64 + wr*32 + fm*16 + l4*4 + rr;
            int gcol = bn*64 + wc*32 + fn*16 + l15;
            obf[(size_t)grow*768 + gcol] = f2bf(gelu_f(acc[fm][fn][rr] + bias[gcol]));
        }
}

// ---------------- full-width N=192 GEMM with f32 full-row epilogue ---------
// MODE 0 (proj): out[orow] = x[orow] + C + bias, orow = rolled window-reverse.
// MODE 1 (FC2):  out[row] += C + bias (out pre-offset to band start).
template<int M_BLK, int MODE>
__global__ __launch_bounds__(256) void gemmN192(
    const unsigned short* __restrict__ A, const unsigned short* __restrict__ Bt,
    const float* __restrict__ bias, int K, int lda, int ldb,
    const float* __restrict__ xres, float* __restrict__ out)
{
    constexpr int MB = M_BLK / 16;
    constexpr int LDS_STAGE = (M_BLK*40 + 192*40) * 2;
    constexpr int LDS_CST   = M_BLK * 180 * 4;
    constexpr int LDSZ = LDS_STAGE > LDS_CST ? LDS_STAGE : LDS_CST;
    __shared__ __align__(16) char lds[LDSZ];
    unsigned short* As = (unsigned short*)lds;
    unsigned short* Bs = As + M_BLK*40;
    float* Cst = (float*)lds;

    const int tid  = threadIdx.x;
    const int bm   = blockIdx.x;
    const int lane = tid & 63;
    const int wv   = tid >> 6;            // 0..3, owns cols [wv*48, wv*48+48)
    const int l15  = lane & 15, l4 = lane >> 4;
    const int r    = tid >> 2;            // 0..63
    const int kk   = (tid & 3) << 3;

    f32x4 acc[MB][3];
    #pragma unroll
    for (int m = 0; m < MB; m++)
        #pragma unroll
        for (int nb = 0; nb < 3; nb++) acc[m][nb] = f32x4{0.f,0.f,0.f,0.f};

    const size_t abase = (size_t)(bm*M_BLK + r) * (size_t)lda + kk;
    const size_t bbase = (size_t)r * (size_t)ldb + kk;

    for (int kt = 0; kt < K; kt += 32) {
        if (M_BLK == 64 || tid < M_BLK*4)
            *(uint4*)&As[r*40 + kk] = *(const uint4*)&A[abase + kt];
        #pragma unroll
        for (int jj = 0; jj < 3; jj++)
            *(uint4*)&Bs[(r + jj*64)*40 + kk] = *(const uint4*)&Bt[bbase + (size_t)jj*64*ldb + kt];
        __syncthreads();
        short8 af[MB], bf[3];
        #pragma unroll
        for (int m = 0; m < MB; m++) af[m] = *(const short8*)&As[(m*16 + l15)*40 + l4*8];
        #pragma unroll
        for (int nb = 0; nb < 3; nb++) bf[nb] = *(const short8*)&Bs[(wv*48 + nb*16 + l15)*40 + l4*8];
        #pragma unroll
        for (int m = 0; m < MB; m++)
            #pragma unroll
            for (int nb = 0; nb < 3; nb++)
                acc[m][nb] = __builtin_amdgcn_mfma_f32_16x16x32_bf16(af[m], bf[nb], acc[m][nb], 0, 0, 0);
        __syncthreads();
    }

    #pragma unroll
    for (int m = 0; m < MB; m++)
      #pragma unroll
      for (int nb = 0; nb < 3; nb++)
        #pragma unroll
        for (int rr = 0; rr < 4; rr++) {
            int tok = m*16 + l4*4 + rr;
            int col = wv*48 + nb*16 + l15;
            if (col < 180) Cst[tok*180 + col] = acc[m][nb][rr];
        }
    __syncthreads();

    for (int idx = tid; idx < M_BLK*4; idx += 256) {
        int tok = idx >> 2, j = idx & 3;
        int c0  = j * 48;
        int cnt = (j == 3) ? 36 : 48;
        size_t orow;
        if (MODE == 0) {
            int grow = bm*M_BLK + tok;
            int wig  = grow >> 6;
            int b_   = wig >> 10, wi = wig & 1023, ti = grow & 63;
            int h2   = (((wi >> 5) << 3) + (ti >> 3) + 4) & 255;
            int w2   = (((wi & 31) << 3) + (ti & 7) + 4) & 255;
            orow = ((size_t)b_ << 16) + (h2 << 8) + w2;
        } else {
            orow = (size_t)(bm*M_BLK + tok);
        }
        float*       op = out  + orow*180 + c0;
        const float* cp = &Cst[tok*180 + c0];
        const float* bb = bias + c0;
        if (MODE == 0) {
            const float* xp = xres + orow*180 + c0;
            for (int i = 0; i < cnt; i += 4) {
                f32x4 ov = *(const f32x4*)&xp[i] + *(const f32x4*)&cp[i] + *(const f32x4*)&bb[i];
                *(f32x4*)&op[i] = ov;
            }
        } else {
            for (int i = 0; i < cnt; i += 4) {
                f32x4 ov = *(const f32x4*)&op[i];
                ov += *(const f32x4*)&cp[i] + *(const f32x4*)&bb[i];
                *(f32x4*)&op[i] = ov;
            }
        }
    }
}

// ---------------- depthwise 3x3 conv + bias + exact GELU (64-row band) -----
__global__ __launch_bounds__(256) void dwconv_band(
    const unsigned short* __restrict__ m1, const float* __restrict__ wT,
    const float* __restrict__ bias, int h0, unsigned short* __restrict__ m2)
{
    const int hl  = blockIdx.x;            // 0..63 (band-local row)
    const int t   = threadIdx.x;
    const int cg  = t & 31;
    const int pl  = t >> 5;                // 0..7
    const int w0  = blockIdx.y * 64 + pl * 8;
    const int c   = blockIdx.z * 256 + cg * 8;   // 0..760

    float acc[8][8];
    float bv[8];
    *(f32x4*)&bv[0] = *(const f32x4*)&bias[c];
    *(f32x4*)&bv[4] = *(const f32x4*)&bias[c + 4];
    #pragma unroll
    for (int p = 0; p < 8; p++)
        #pragma unroll
        for (int i = 0; i < 8; i++) acc[p][i] = bv[i];

    const short8 zv = {0,0,0,0,0,0,0,0};
    #pragma unroll
    for (int dh = -1; dh <= 1; dh++) {
        int hg = h0 + hl + dh;
        if (hg < 0 || hg > 255) continue;
        const unsigned short* rb = m1 + (size_t)(hl + 1 + dh) * 256 * 768 + c;
        float f[10][8];
        #pragma unroll
        for (int j = 0; j < 10; j++) {
            int w2 = w0 - 1 + j;
            short8 v = (w2 < 0 || w2 > 255) ? zv : *(const short8*)&rb[(size_t)w2*768];
            #pragma unroll
            for (int i = 0; i < 8; i++) f[j][i] = bf2f((unsigned short)v[i]);
        }
        #pragma unroll
        for (int dw2 = 0; dw2 < 3; dw2++) {
            const float* wrow = wT + ((dh+1)*3 + dw2)*768 + c;
            float wt[8];
            *(f32x4*)&wt[0] = *(const f32x4*)&wrow[0];
            *(f32x4*)&wt[4] = *(const f32x4*)&wrow[4];
            #pragma unroll
            for (int p = 0; p < 8; p++)
                #pragma unroll
                for (int i = 0; i < 8; i++)
                    acc[p][i] += f[p + dw2][i] * wt[i];
        }
    }
    unsigned short* ob = m2 + ((size_t)hl*256 + w0)*768 + c;
    #pragma unroll
    for (int p = 0; p < 8; p++) {
        short8 o;
        #pragma unroll
        for (int i = 0; i < 8; i++) o[i] = (short)f2bf(gelu_f(acc[p][i]));
        *(short8*)&ob[(size_t)p*768] = o;
    }
}

extern "C" void kernel_launch(void* const* d_in, const int* in_sizes, int n_in,
                              void* d_out, int out_size, void* d_ws, size_t ws_size,
                              hipStream_t stream) {
    (void)in_sizes; (void)n_in; (void)out_size;
    if (ws_size < WS_NEEDED) return;
    const float* x      = (const float*)d_in[0];
    const float* n1g    = (const float*)d_in[1];
    const float* n1b    = (const float*)d_in[2];
    const float* qkv_w  = (const float*)d_in[3];
    const float* qkv_b  = (const float*)d_in[4];
    const float* rpt    = (const float*)d_in[5];
    const float* proj_w = (const float*)d_in[6];
    const float* proj_b = (const float*)d_in[7];
    const float* n2g    = (const float*)d_in[8];
    const float* n2b    = (const float*)d_in[9];
    const float* fc1_w  = (const float*)d_in[10];
    const float* fc1_b  = (const float*)d_in[11];
    const float* dw_w   = (const float*)d_in[12];
    const float* dw_b   = (const float*)d_in[13];
    const float* fc2_w  = (const float*)d_in[14];
    const float* fc2_b  = (const float*)d_in[15];
    float* out = (float*)d_out;
    char*  ws  = (char*)d_ws;

    unsigned short* wq2  = (unsigned short*)(ws + OFF_WQ);
    unsigned short* wp   = (unsigned short*)(ws + OFF_WP);
    unsigned short* wf1  = (unsigned short*)(ws + OFF_WF1);
    unsigned short* wf2t = (unsigned short*)(ws + OFF_WF2T);
    float* bq2   = (float*)(ws + OFF_BQ);
    float* bp    = (float*)(ws + OFF_BP);
    float* bf1   = (float*)(ws + OFF_BF1);
    float* bf2   = (float*)(ws + OFF_BF2);
    float* biasf = (float*)(ws + OFF_BIASF);
    float* wdwT  = (float*)(ws + OFF_WDWT);
    float* bdw   = (float*)(ws + OFF_BDW);
    unsigned short* R1 = (unsigned short*)(ws + OFF_R1);  // xw -> attn_out -> xn2
    unsigned short* R2 = (unsigned short*)(ws + OFF_R2);  // m1 band
    unsigned short* R3 = (unsigned short*)(ws + OFF_R3);  // m2 band

    prep_kernel<<<1861, 256, 0, stream>>>(qkv_w, qkv_b, proj_w, proj_b, fc1_w, fc1_b,
                                          fc2_w, fc2_b, rpt, dw_w, dw_b,
                                          wq2, wp, wf1, wf2t,
                                          bq2, bp, bf1, bf2, biasf, wdwT, bdw);
    // LN1 + shift + window partition -> xw (R1, pads zeroed)
    ln_kernel<1><<<32768, 256, 0, stream>>>(x, n1g, n1b, R1);
    // fused QKV + attention, in-place on R1
    fused_qkv_attn<<<2048, 384, 0, stream>>>(R1, wq2, bq2, biasf);
    // proj + window-reverse + residual -> d_out (x1), full-row epilogue
    gemmN192<64, 0><<<2048, 256, 0, stream>>>(R1, wp, bp, 192, 192, 192, x, out);
    // LN2 -> xn2 (R1)
    ln_kernel<0><<<32768, 256, 0, stream>>>(out, n2g, n2b, R1);
    // MLP in 8 row-bands of 64 (halo'd FC1; single-pass K=768 FC2)
    for (int band = 0; band < 8; ++band) {
        const int b_img   = band >> 2;
        const int h0      = (band & 3) * 64;
        const int h_start = (h0 == 0) ? 0 : h0 - 1;
        const int h_end   = (h0 + 64 < 256) ? (h0 + 65) : 256;
        const int n_rows  = h_end - h_start;
        const int moff    = (h0 == 0) ? 1 : 0;
        const size_t arow0 = ((size_t)b_img*256 + h_start) * 256;
        const size_t pix0  = ((size_t)b_img*256 + h0) * 256;
        fc1_gemm64<<<dim3(n_rows*4, 12), 256, 0, stream>>>(
            R1 + arow0*192, wf1, bf1, R2 + (size_t)moff*256*768);
        dwconv_band<<<dim3(64, 4, 3), 256, 0, stream>>>(R2, wdwT, bdw, h0, R3);
        gemmN192<32, 1><<<512, 256, 0, stream>>>(
            R3, wf2t, bf2, 768, 768, 768, nullptr, out + pix0*180);
    }
}